// Round 14
// baseline (391.437 us; speedup 1.0000x reference)
//
#include <hip/hip_runtime.h>
#include <hip/hip_bf16.h>
#include <hip/hip_fp16.h>
#include <math.h>

#define NN 50000
#define NE 800000

typedef unsigned short ushort_t;
typedef unsigned int uint_t;
typedef __attribute__((ext_vector_type(8))) short bf16x8;
typedef __attribute__((ext_vector_type(4))) float f32x4;

__device__ __forceinline__ float lrelu(float x) { return x >= 0.f ? x : 0.2f * x; }

__device__ __forceinline__ ushort_t f2bf_rn(float f) {
  uint_t u = __builtin_bit_cast(uint_t, f);
  uint_t r = u + 0x7FFFu + ((u >> 16) & 1u);
  return (ushort_t)(r >> 16);
}
__device__ __forceinline__ float bf2f(ushort_t h) {
  uint_t u = ((uint_t)h) << 16;
  return __builtin_bit_cast(float, u);
}
__device__ __forceinline__ ushort_t f2h_bits(float f) {
  __half h = __float2half(f);
  return __builtin_bit_cast(ushort_t, h);
}
// order-preserving float<->uint key (for atomicMax on float values)
__device__ __forceinline__ uint_t fkey(float f) {
  uint_t b = __builtin_bit_cast(uint_t, f);
  return (b & 0x80000000u) ? ~b : (b | 0x80000000u);
}
__device__ __forceinline__ float fdec(uint_t k) {
  uint_t b = (k & 0x80000000u) ? (k & 0x7fffffffu) : ~k;
  return __builtin_bit_cast(float, b);
}

// ---------------- zero counts + smax keys ----------------
__global__ __launch_bounds__(256) void zero_kernel(int* __restrict__ p, int n,
                                                   uint_t* __restrict__ keys) {
  int i = blockIdx.x * 256 + threadIdx.x;
  if (i < n) p[i] = 0;
  if (blockIdx.x == 0 && threadIdx.x < 8) keys[threadIdx.x] = 0;  // key 0 == -inf-ish
}

// ---------------- W prep: transpose + bf16 hi/lo split. W[K][C] -> wt[C][K] ----------------
__device__ __forceinline__ void prep_dev(const float* __restrict__ W, int Kdim, int C,
                                         ushort_t* __restrict__ wth, ushort_t* __restrict__ wtl,
                                         int t) {
  int nk = Kdim >> 4;
  if (t >= C * nk) return;
  int c = t / nk, kc = (t % nk) << 4;
  uint_t hw[8], lw[8];
#pragma unroll
  for (int i = 0; i < 8; ++i) {
    float f0 = W[(size_t)(kc + 2 * i) * C + c];
    float f1 = W[(size_t)(kc + 2 * i + 1) * C + c];
    ushort_t h0 = f2bf_rn(f0), h1 = f2bf_rn(f1);
    ushort_t l0 = f2bf_rn(f0 - bf2f(h0)), l1 = f2bf_rn(f1 - bf2f(h1));
    hw[i] = (uint_t)h0 | ((uint_t)h1 << 16);
    lw[i] = (uint_t)l0 | ((uint_t)l1 << 16);
  }
  uint_t* ph = (uint_t*)&wth[(size_t)c * Kdim + kc];
  uint_t* pl = (uint_t*)&wtl[(size_t)c * Kdim + kc];
  *(uint4*)ph = make_uint4(hw[0], hw[1], hw[2], hw[3]);
  *(uint4*)(ph + 4) = make_uint4(hw[4], hw[5], hw[6], hw[7]);
  *(uint4*)pl = make_uint4(lw[0], lw[1], lw[2], lw[3]);
  *(uint4*)(pl + 4) = make_uint4(lw[4], lw[5], lw[6], lw[7]);
}

// ---------------- setup: edge count + all W preps (block-specialized) ----------------
#define CNT_BLOCKS 3125
__global__ __launch_bounds__(256) void setup_kernel(const int* __restrict__ ei,
                                                    int* __restrict__ counts,
                                                    const float* __restrict__ W0, ushort_t* wt0h, ushort_t* wt0l,
                                                    const float* __restrict__ W1, ushort_t* wt1h, ushort_t* wt1l,
                                                    const float* __restrict__ W2, ushort_t* wt2h, ushort_t* wt2l,
                                                    const float* __restrict__ Wv, const float* __restrict__ Wt,
                                                    ushort_t* wHh, ushort_t* wHl) {
  int b = blockIdx.x;
  if (b < CNT_BLOCKS) {
    int e = b * 256 + threadIdx.x;
    if (e < NE) atomicAdd(&counts[ei[NE + e]], 1);
    return;
  }
  b -= CNT_BLOCKS;
  if (b < 16) { prep_dev(W0, 512, 128, wt0h, wt0l, b * 256 + threadIdx.x); return; }
  b -= 16;
  if (b < 4) { prep_dev(W1, 128, 128, wt1h, wt1l, b * 256 + threadIdx.x); return; }
  b -= 4;
  if (b < 2) { prep_dev(W2, 128, 64, wt2h, wt2l, b * 256 + threadIdx.x); return; }
  b -= 2;
  if (b < 1) { prep_dev(Wv, 64, 64, wHh, wHl, b * 256 + threadIdx.x); return; }
  b -= 1;
  prep_dev(Wt, 64, 64, wHh + 64 * 64, wHl + 64 * 64, b * 256 + threadIdx.x);
}

// ---------------- hierarchical scan ----------------
__global__ __launch_bounds__(256) void scan_blocksum_kernel(const int* __restrict__ counts,
                                                            int* __restrict__ bsums, int n) {
  __shared__ int red[4];
  int i = blockIdx.x * 256 + threadIdx.x;
  int v = (i < n) ? counts[i] : 0;
#pragma unroll
  for (int off = 32; off > 0; off >>= 1) v += __shfl_down(v, off);
  if ((threadIdx.x & 63) == 0) red[threadIdx.x >> 6] = v;
  __syncthreads();
  if (threadIdx.x == 0) bsums[blockIdx.x] = red[0] + red[1] + red[2] + red[3];
}

__global__ __launch_bounds__(256) void scan_offsets_kernel(int* __restrict__ bsums, int nb) {
  __shared__ int sm[256];
  int tid = threadIdx.x;
  int v = (tid < nb) ? bsums[tid] : 0;
  sm[tid] = v;
  __syncthreads();
  for (int off = 1; off < 256; off <<= 1) {
    int u = (tid >= off) ? sm[tid - off] : 0;
    __syncthreads();
    sm[tid] += u;
    __syncthreads();
  }
  if (tid < nb) bsums[tid] = sm[tid] - v;  // exclusive
}

__global__ __launch_bounds__(256) void scan_final_kernel(const int* __restrict__ counts,
                                                         const int* __restrict__ boffs,
                                                         int* __restrict__ row_ptr,
                                                         int* __restrict__ cursor, int n, int E) {
  __shared__ int sm[256];
  int tid = threadIdx.x;
  int i = blockIdx.x * 256 + tid;
  int v = (i < n) ? counts[i] : 0;
  int orig = v;
  sm[tid] = v;
  __syncthreads();
  for (int off = 1; off < 256; off <<= 1) {
    int u = (tid >= off) ? sm[tid - off] : 0;
    __syncthreads();
    sm[tid] += u;
    __syncthreads();
  }
  if (i < n) {
    row_ptr[i] = boffs[blockIdx.x] + sm[tid] - orig;
    cursor[i] = 0;
  }
  if (i == n) row_ptr[n] = E;
}

__global__ void fill_kernel(const int* __restrict__ ei, const int* __restrict__ row_ptr,
                            int* __restrict__ cursor, int* __restrict__ col_src, int E) {
  int e = blockIdx.x * blockDim.x + threadIdx.x;
  if (e < E) {
    int d = ei[E + e];
    int pos = row_ptr[d] + atomicAdd(&cursor[d], 1);
    col_src[pos] = ei[e];
  }
}

// ---------------- MFMA GEMM 64x128 tile + fused att2 epilogue (+ global s-max atomics) ----------------
// r9 structure: LDS staging, stride 40 ushorts, 2 barriers/k-tile, 64-row tiles, LB(256,4).
template <int K, bool SPLIT>
__global__ __launch_bounds__(256, 4) void gemm_att128_kernel(const float* __restrict__ Af,
                                                             const ushort_t* __restrict__ Ahp,
                                                             const ushort_t* __restrict__ Alp,
                                                             const ushort_t* __restrict__ wth,
                                                             const ushort_t* __restrict__ wtl,
                                                             const float* __restrict__ a_src,
                                                             const float* __restrict__ a_dst,
                                                             __half2* __restrict__ h2h,
                                                             float* __restrict__ s_arr,
                                                             float* __restrict__ t_arr,
                                                             uint_t* __restrict__ smax, int n) {
  __shared__ __align__(16) ushort_t smem[15360];  // 30.7 KB
  ushort_t (*ah)[40] = (ushort_t(*)[40])smem;                 // [64][40]
  ushort_t (*al)[40] = (ushort_t(*)[40])(smem + 2560);        // [64][40]
  ushort_t (*bh)[40] = (ushort_t(*)[40])(smem + 5120);        // [128][40]
  ushort_t (*bl)[40] = (ushort_t(*)[40])(smem + 10240);       // [128][40]

  const int t = threadIdx.x;
  const int row0 = blockIdx.x * 64;
  const int asrow = t >> 2, akc = (t & 3) * 8;
  const int bcol = t >> 1, bkc = (t & 1) * 16;

  const int lane = t & 63;
  const int wid = t >> 6;
  const int wm = wid >> 1, wn = wid & 1;
  const int r16 = lane & 15, g = lane >> 4;

  f32x4 acc[2][4];
#pragma unroll
  for (int i = 0; i < 2; ++i)
#pragma unroll
    for (int j = 0; j < 4; ++j) acc[i][j] = (f32x4)(0.f);

  for (int kt = 0; kt < K / 32; ++kt) {
    const int k0 = kt * 32;
    // ---- stage A ----
    if (SPLIT) {
      uint4 vh = make_uint4(0, 0, 0, 0), vl = vh;
      if (row0 + asrow < n) {
        vh = *(const uint4*)&Ahp[(size_t)(row0 + asrow) * K + k0 + akc];
        vl = *(const uint4*)&Alp[(size_t)(row0 + asrow) * K + k0 + akc];
      }
      *(uint4*)&ah[asrow][akc] = vh;
      *(uint4*)&al[asrow][akc] = vl;
    } else {
      uint_t hw[4], lw[4];
      if (row0 + asrow < n) {
        const float* ap = &Af[(size_t)(row0 + asrow) * K + k0 + akc];
#pragma unroll
        for (int j = 0; j < 2; ++j) {
          float4 v = *(const float4*)(ap + j * 4);
          ushort_t h0 = f2bf_rn(v.x), h1 = f2bf_rn(v.y), h2 = f2bf_rn(v.z), h3 = f2bf_rn(v.w);
          ushort_t l0 = f2bf_rn(v.x - bf2f(h0)), l1 = f2bf_rn(v.y - bf2f(h1));
          ushort_t l2 = f2bf_rn(v.z - bf2f(h2)), l3 = f2bf_rn(v.w - bf2f(h3));
          hw[j * 2] = (uint_t)h0 | ((uint_t)h1 << 16);
          hw[j * 2 + 1] = (uint_t)h2 | ((uint_t)h3 << 16);
          lw[j * 2] = (uint_t)l0 | ((uint_t)l1 << 16);
          lw[j * 2 + 1] = (uint_t)l2 | ((uint_t)l3 << 16);
        }
      } else {
#pragma unroll
        for (int j = 0; j < 4; ++j) { hw[j] = 0; lw[j] = 0; }
      }
      *(uint4*)&ah[asrow][akc] = make_uint4(hw[0], hw[1], hw[2], hw[3]);
      *(uint4*)&al[asrow][akc] = make_uint4(lw[0], lw[1], lw[2], lw[3]);
    }
    // ---- stage B ----
    {
      const ushort_t* ph = &wth[(size_t)bcol * K + k0 + bkc];
      const ushort_t* pl = &wtl[(size_t)bcol * K + k0 + bkc];
      *(uint4*)&bh[bcol][bkc] = *(const uint4*)ph;
      *(uint4*)&bh[bcol][bkc + 8] = *(const uint4*)(ph + 8);
      *(uint4*)&bl[bcol][bkc] = *(const uint4*)pl;
      *(uint4*)&bl[bcol][bkc + 8] = *(const uint4*)(pl + 8);
    }
    __syncthreads();

    bf16x8 fah[2], fal[2], fbh[4], fbl[4];
#pragma unroll
    for (int mf = 0; mf < 2; ++mf) {
      fah[mf] = *(const bf16x8*)&ah[wm * 32 + mf * 16 + r16][g * 8];
      fal[mf] = *(const bf16x8*)&al[wm * 32 + mf * 16 + r16][g * 8];
    }
#pragma unroll
    for (int nf = 0; nf < 4; ++nf) {
      fbh[nf] = *(const bf16x8*)&bh[wn * 64 + nf * 16 + r16][g * 8];
      fbl[nf] = *(const bf16x8*)&bl[wn * 64 + nf * 16 + r16][g * 8];
    }
#pragma unroll
    for (int mf = 0; mf < 2; ++mf)
#pragma unroll
      for (int nf = 0; nf < 4; ++nf) {
        acc[mf][nf] = __builtin_amdgcn_mfma_f32_16x16x32_bf16(fah[mf], fbh[nf], acc[mf][nf], 0, 0, 0);
        acc[mf][nf] = __builtin_amdgcn_mfma_f32_16x16x32_bf16(fah[mf], fbl[nf], acc[mf][nf], 0, 0, 0);
        acc[mf][nf] = __builtin_amdgcn_mfma_f32_16x16x32_bf16(fal[mf], fbh[nf], acc[mf][nf], 0, 0, 0);
      }
    __syncthreads();
  }

  // ---- fused att epilogue: s,t + wave-level global s-max ----
  const int head = wn;
  float asv[4], adv[4];
#pragma unroll
  for (int nf = 0; nf < 4; ++nf) {
    asv[nf] = a_src[head * 64 + nf * 16 + r16];
    adv[nf] = a_dst[head * 64 + nf * 16 + r16];
  }
  float smax_local = -3.4e38f;
#pragma unroll
  for (int mf = 0; mf < 2; ++mf) {
#pragma unroll
    for (int reg = 0; reg < 4; ++reg) {
      float sp = 0.f, tp = 0.f;
#pragma unroll
      for (int nf = 0; nf < 4; ++nf) {
        sp = fmaf(acc[mf][nf][reg], asv[nf], sp);
        tp = fmaf(acc[mf][nf][reg], adv[nf], tp);
      }
#pragma unroll
      for (int off = 1; off < 16; off <<= 1) {
        sp += __shfl_xor(sp, off);
        tp += __shfl_xor(tp, off);
      }
      smax_local = fmaxf(smax_local, sp);
      int row = row0 + wm * 32 + mf * 16 + g * 4 + reg;
      if (r16 == 0 && row < n) {
        s_arr[row * 2 + head] = sp;
        t_arr[row * 2 + head] = tp;
      }
    }
  }
  smax_local = fmaxf(smax_local, __shfl_xor(smax_local, 16));
  smax_local = fmaxf(smax_local, __shfl_xor(smax_local, 32));
  if (lane == 0) atomicMax(&smax[head], fkey(smax_local));

  // ---- f16 repack via LDS, coalesced h2h store (interleaved heads) ----
  ushort_t* hstage = smem;  // [64][136], 272 B stride (16-aligned)
#pragma unroll
  for (int mf = 0; mf < 2; ++mf)
#pragma unroll
    for (int nf = 0; nf < 4; ++nf)
#pragma unroll
      for (int reg = 0; reg < 4; ++reg) {
        int rl = wm * 32 + mf * 16 + g * 4 + reg;
        int col = (nf * 16 + r16) * 2 + head;
        hstage[rl * 136 + col] = f2h_bits(acc[mf][nf][reg]);
      }
  __syncthreads();
#pragma unroll
  for (int it = 0; it < 4; ++it) {
    int idx = t + it * 256;
    int r = idx >> 4, ch = idx & 15;
    if (row0 + r < n) {
      *(uint4*)((char*)h2h + (size_t)(row0 + r) * 256 + ch * 16) =
          *(const uint4*)&hstage[r * 136 + ch * 8];
    }
  }
}

// ---------------- MFMA GEMM 64x64 + fused att1 (layer 2, K=128, pre-split A) ----------------
__global__ __launch_bounds__(256, 4) void gemm_att64_kernel(const ushort_t* __restrict__ Ahp,
                                                            const ushort_t* __restrict__ Alp,
                                                            const ushort_t* __restrict__ wth,
                                                            const ushort_t* __restrict__ wtl,
                                                            const float* __restrict__ a_src,
                                                            const float* __restrict__ a_dst,
                                                            __half* __restrict__ h16,
                                                            float* __restrict__ s1,
                                                            float* __restrict__ t1,
                                                            uint_t* __restrict__ smax, int n) {
  constexpr int K = 128;
  __shared__ __align__(16) ushort_t smem[10240];  // 20.5 KB
  ushort_t (*ah)[40] = (ushort_t(*)[40])smem;
  ushort_t (*al)[40] = (ushort_t(*)[40])(smem + 2560);
  ushort_t (*bh)[40] = (ushort_t(*)[40])(smem + 5120);
  ushort_t (*bl)[40] = (ushort_t(*)[40])(smem + 7680);

  const int t = threadIdx.x;
  const int row0 = blockIdx.x * 64;
  const int asrow = t >> 2, akc = (t & 3) * 8;
  const bool arow_ok = (row0 + asrow) < n;

  const int lane = t & 63;
  const int wid = t >> 6;
  const int r16 = lane & 15, g = lane >> 4;

  f32x4 acc[4];
#pragma unroll
  for (int j = 0; j < 4; ++j) acc[j] = (f32x4)(0.f);

  for (int kt = 0; kt < K / 32; ++kt) {
    const int k0 = kt * 32;
    {
      uint4 vh = make_uint4(0, 0, 0, 0), vl = vh;
      if (arow_ok) {
        vh = *(const uint4*)&Ahp[(size_t)(row0 + asrow) * K + k0 + akc];
        vl = *(const uint4*)&Alp[(size_t)(row0 + asrow) * K + k0 + akc];
      }
      *(uint4*)&ah[asrow][akc] = vh;
      *(uint4*)&al[asrow][akc] = vl;
    }
    {
      *(uint4*)&bh[asrow][akc] = *(const uint4*)&wth[(size_t)asrow * K + k0 + akc];
      *(uint4*)&bl[asrow][akc] = *(const uint4*)&wtl[(size_t)asrow * K + k0 + akc];
    }
    __syncthreads();

    bf16x8 fahv, falv, fbh[4], fbl[4];
    fahv = *(const bf16x8*)&ah[wid * 16 + r16][g * 8];
    falv = *(const bf16x8*)&al[wid * 16 + r16][g * 8];
#pragma unroll
    for (int nf = 0; nf < 4; ++nf) {
      fbh[nf] = *(const bf16x8*)&bh[nf * 16 + r16][g * 8];
      fbl[nf] = *(const bf16x8*)&bl[nf * 16 + r16][g * 8];
    }
#pragma unroll
    for (int nf = 0; nf < 4; ++nf) {
      acc[nf] = __builtin_amdgcn_mfma_f32_16x16x32_bf16(fahv, fbh[nf], acc[nf], 0, 0, 0);
      acc[nf] = __builtin_amdgcn_mfma_f32_16x16x32_bf16(fahv, fbl[nf], acc[nf], 0, 0, 0);
      acc[nf] = __builtin_amdgcn_mfma_f32_16x16x32_bf16(falv, fbh[nf], acc[nf], 0, 0, 0);
    }
    __syncthreads();
  }

  float asv[4], adv[4];
#pragma unroll
  for (int nf = 0; nf < 4; ++nf) {
    asv[nf] = a_src[nf * 16 + r16];
    adv[nf] = a_dst[nf * 16 + r16];
  }
  float smax_local = -3.4e38f;
#pragma unroll
  for (int reg = 0; reg < 4; ++reg) {
    float sp = 0.f, tp = 0.f;
#pragma unroll
    for (int nf = 0; nf < 4; ++nf) {
      sp = fmaf(acc[nf][reg], asv[nf], sp);
      tp = fmaf(acc[nf][reg], adv[nf], tp);
    }
#pragma unroll
    for (int off = 1; off < 16; off <<= 1) {
      sp += __shfl_xor(sp, off);
      tp += __shfl_xor(tp, off);
    }
    smax_local = fmaxf(smax_local, sp);
    int row = row0 + wid * 16 + g * 4 + reg;
    if (r16 == 0 && row < n) {
      s1[row] = sp;
      t1[row] = tp;
    }
  }
  smax_local = fmaxf(smax_local, __shfl_xor(smax_local, 16));
  smax_local = fmaxf(smax_local, __shfl_xor(smax_local, 32));
  if (lane == 0) atomicMax(smax, fkey(smax_local));

  ushort_t* hstage = smem;  // [64][72]
#pragma unroll
  for (int nf = 0; nf < 4; ++nf)
#pragma unroll
    for (int reg = 0; reg < 4; ++reg) {
      int rl = wid * 16 + g * 4 + reg;
      hstage[rl * 72 + nf * 16 + r16] = f2h_bits(acc[nf][reg]);
    }
  __syncthreads();
#pragma unroll
  for (int it = 0; it < 2; ++it) {
    int idx = t + it * 256;
    int r = idx >> 3, ch = idx & 7;
    if (row0 + r < n) {
      *(uint4*)((char*)h16 + (size_t)(row0 + r) * 128 + ch * 16) =
          *(const uint4*)&hstage[r * 72 + ch * 8];
    }
  }
}

// ---------------- MFMA GEMM 64x128: both MLP heads, K=64, pre-split A ----------------
__global__ __launch_bounds__(256, 4) void gemm_heads_kernel(const ushort_t* __restrict__ Ahp,
                                                            const ushort_t* __restrict__ Alp,
                                                            const ushort_t* __restrict__ wth,
                                                            const ushort_t* __restrict__ wtl,
                                                            const float* __restrict__ bv,
                                                            const float* __restrict__ bt,
                                                            float* __restrict__ out_v,
                                                            float* __restrict__ out_t, int n) {
  constexpr int K = 64;
  __shared__ __align__(16) ushort_t smem[15360];
  ushort_t (*ah)[40] = (ushort_t(*)[40])smem;
  ushort_t (*al)[40] = (ushort_t(*)[40])(smem + 2560);
  ushort_t (*bh)[40] = (ushort_t(*)[40])(smem + 5120);
  ushort_t (*bl)[40] = (ushort_t(*)[40])(smem + 10240);

  const int t = threadIdx.x;
  const int row0 = blockIdx.x * 64;
  const int asrow = t >> 2, akc = (t & 3) * 8;
  const int bcol = t >> 1, bkc = (t & 1) * 16;
  const bool arow_ok = (row0 + asrow) < n;

  const int lane = t & 63;
  const int wid = t >> 6;
  const int wm = wid >> 1, wn = wid & 1;
  const int r16 = lane & 15, g = lane >> 4;

  f32x4 acc[2][4];
#pragma unroll
  for (int i = 0; i < 2; ++i)
#pragma unroll
    for (int j = 0; j < 4; ++j) acc[i][j] = (f32x4)(0.f);

  for (int kt = 0; kt < K / 32; ++kt) {
    const int k0 = kt * 32;
    {
      uint4 vh = make_uint4(0, 0, 0, 0), vl = vh;
      if (arow_ok) {
        vh = *(const uint4*)&Ahp[(size_t)(row0 + asrow) * K + k0 + akc];
        vl = *(const uint4*)&Alp[(size_t)(row0 + asrow) * K + k0 + akc];
      }
      *(uint4*)&ah[asrow][akc] = vh;
      *(uint4*)&al[asrow][akc] = vl;
    }
    {
      const ushort_t* ph = &wth[(size_t)bcol * K + k0 + bkc];
      const ushort_t* pl = &wtl[(size_t)bcol * K + k0 + bkc];
      *(uint4*)&bh[bcol][bkc] = *(const uint4*)ph;
      *(uint4*)&bh[bcol][bkc + 8] = *(const uint4*)(ph + 8);
      *(uint4*)&bl[bcol][bkc] = *(const uint4*)pl;
      *(uint4*)&bl[bcol][bkc + 8] = *(const uint4*)(pl + 8);
    }
    __syncthreads();

    bf16x8 fah[2], fal[2], fbh[4], fbl[4];
#pragma unroll
    for (int mf = 0; mf < 2; ++mf) {
      fah[mf] = *(const bf16x8*)&ah[wm * 32 + mf * 16 + r16][g * 8];
      fal[mf] = *(const bf16x8*)&al[wm * 32 + mf * 16 + r16][g * 8];
    }
#pragma unroll
    for (int nf = 0; nf < 4; ++nf) {
      fbh[nf] = *(const bf16x8*)&bh[wn * 64 + nf * 16 + r16][g * 8];
      fbl[nf] = *(const bf16x8*)&bl[wn * 64 + nf * 16 + r16][g * 8];
    }
#pragma unroll
    for (int mf = 0; mf < 2; ++mf)
#pragma unroll
      for (int nf = 0; nf < 4; ++nf) {
        acc[mf][nf] = __builtin_amdgcn_mfma_f32_16x16x32_bf16(fah[mf], fbh[nf], acc[mf][nf], 0, 0, 0);
        acc[mf][nf] = __builtin_amdgcn_mfma_f32_16x16x32_bf16(fah[mf], fbl[nf], acc[mf][nf], 0, 0, 0);
        acc[mf][nf] = __builtin_amdgcn_mfma_f32_16x16x32_bf16(fal[mf], fbh[nf], acc[mf][nf], 0, 0, 0);
      }
    __syncthreads();
  }

  const float* bias = wn ? bt : bv;
  float* outp = wn ? out_t : out_v;
#pragma unroll
  for (int mf = 0; mf < 2; ++mf) {
#pragma unroll
    for (int reg = 0; reg < 4; ++reg) {
      int row = row0 + wm * 32 + mf * 16 + g * 4 + reg;
      if (row < n) {
#pragma unroll
        for (int nf = 0; nf < 4; ++nf) {
          int c = nf * 16 + r16;
          outp[(size_t)row * 64 + c] = fmaxf(acc[mf][nf][reg] + bias[c], 0.f);
        }
      }
    }
  }
}

// ---------------- bound-softmax aggregation, H=2 (no max pass) -> bf16-split planes ----------------
__global__ __launch_bounds__(256) void agg2_kernel(const __half2* __restrict__ h2h,
                                                   const float2* __restrict__ s2,
                                                   const float2* __restrict__ t2,
                                                   const int* __restrict__ row_ptr,
                                                   const int* __restrict__ col_src,
                                                   const float* __restrict__ bias,
                                                   const uint_t* __restrict__ smax,
                                                   ushort_t* __restrict__ outh,
                                                   ushort_t* __restrict__ outl, int n) {
  int wid = (blockIdx.x * 256 + threadIdx.x) >> 6;
  int lane = threadIdx.x & 63;
  if (wid >= n) return;
  const int node = wid;
  const float smax0 = fdec(smax[0]);
  const float smax1 = fdec(smax[1]);
  const float2 tt = t2[node];
  const float t0 = tt.x, t1 = tt.y;
  const float m0 = lrelu(smax0 + t0);   // upper bound on all e0 for this dst
  const float m1 = lrelu(smax1 + t1);
  const int beg = row_ptr[node], end = row_ptr[node + 1];

  float2 sself = s2[node];
  float p0 = __expf(lrelu(sself.x + t0) - m0);
  float p1 = __expf(lrelu(sself.y + t1) - m1);
  float dp0 = 0.f, dp1 = 0.f;  // per-lane partial denominators
  float2 hself = __half22float2(h2h[(size_t)node * 64 + lane]);
  float acc0 = p0 * hself.x;
  float acc1 = p1 * hself.y;

  for (int base = beg; base < end; base += 64) {
    int i = base + lane;
    int srcn = node;
    float q0 = 0.f, q1 = 0.f;
    if (i < end) {
      srcn = col_src[i];
      float2 sv = s2[srcn];
      q0 = __expf(lrelu(sv.x + t0) - m0);
      q1 = __expf(lrelu(sv.y + t1) - m1);
      dp0 += q0;
      dp1 += q1;
    }
    const int cnt = min(64, end - base);
    const int cnt4 = (cnt + 3) & ~3;
    int i0 = __shfl(srcn, 0), i1 = __shfl(srcn, 1), i2 = __shfl(srcn, 2), i3 = __shfl(srcn, 3);
    __half2 b0 = h2h[(size_t)i0 * 64 + lane];
    __half2 b1 = h2h[(size_t)i1 * 64 + lane];
    __half2 b2 = h2h[(size_t)i2 * 64 + lane];
    __half2 b3 = h2h[(size_t)i3 * 64 + lane];
    for (int j = 0; j < cnt4; j += 4) {
      float p00 = __shfl(q0, j),     p01 = __shfl(q1, j);
      float p10 = __shfl(q0, j + 1), p11 = __shfl(q1, j + 1);
      float p20 = __shfl(q0, j + 2), p21 = __shfl(q1, j + 2);
      float p30 = __shfl(q0, j + 3), p31 = __shfl(q1, j + 3);
      __half2 c0 = b0, c1 = b1, c2 = b2, c3 = b3;
      if (j + 4 < cnt4) {
        int n0 = __shfl(srcn, j + 4), n1 = __shfl(srcn, j + 5);
        int n2 = __shfl(srcn, j + 6), n3 = __shfl(srcn, j + 7);
        b0 = h2h[(size_t)n0 * 64 + lane];
        b1 = h2h[(size_t)n1 * 64 + lane];
        b2 = h2h[(size_t)n2 * 64 + lane];
        b3 = h2h[(size_t)n3 * 64 + lane];
      }
      float2 f0 = __half22float2(c0), f1 = __half22float2(c1);
      float2 f2 = __half22float2(c2), f3 = __half22float2(c3);
      acc0 = fmaf(p00, f0.x, acc0);
      acc1 = fmaf(p01, f0.y, acc1);
      acc0 = fmaf(p10, f1.x, acc0);
      acc1 = fmaf(p11, f1.y, acc1);
      acc0 = fmaf(p20, f2.x, acc0);
      acc1 = fmaf(p21, f2.y, acc1);
      acc0 = fmaf(p30, f3.x, acc0);
      acc1 = fmaf(p31, f3.y, acc1);
    }
  }

  // reduce partial denominators across the wave
#pragma unroll
  for (int off = 32; off > 0; off >>= 1) {
    dp0 += __shfl_xor(dp0, off);
    dp1 += __shfl_xor(dp1, off);
  }
  const float d0 = dp0 + p0;
  const float d1 = dp1 + p1;

  float o0 = fmaxf(acc0 / (d0 + 1e-16f) + bias[lane], 0.f);
  float o1 = fmaxf(acc1 / (d1 + 1e-16f) + bias[64 + lane], 0.f);
  ushort_t h0h = f2bf_rn(o0), h1h = f2bf_rn(o1);
  outh[(size_t)node * 128 + lane] = h0h;
  outh[(size_t)node * 128 + 64 + lane] = h1h;
  outl[(size_t)node * 128 + lane] = f2bf_rn(o0 - bf2f(h0h));
  outl[(size_t)node * 128 + 64 + lane] = f2bf_rn(o1 - bf2f(h1h));
}

// ---------------- bound-softmax aggregation, H=1 -> f32 out + bf16-split planes ----------------
__global__ __launch_bounds__(256) void agg1_kernel(const __half* __restrict__ h16,
                                                   const float* __restrict__ s,
                                                   const float* __restrict__ t,
                                                   const int* __restrict__ row_ptr,
                                                   const int* __restrict__ col_src,
                                                   const float* __restrict__ bias,
                                                   const uint_t* __restrict__ smax,
                                                   float* __restrict__ out,
                                                   ushort_t* __restrict__ outh,
                                                   ushort_t* __restrict__ outl, int n) {
  int wid = (blockIdx.x * 256 + threadIdx.x) >> 6;
  int lane = threadIdx.x & 63;
  if (wid >= n) return;
  const int node = wid;
  const float t0 = t[node];
  const float m0 = lrelu(fdec(smax[0]) + t0);
  const int beg = row_ptr[node], end = row_ptr[node + 1];

  float p = __expf(lrelu(s[node] + t0) - m0);
  float dp = 0.f;
  float acc0 = p * __half2float(h16[(size_t)node * 64 + lane]);

  for (int base = beg; base < end; base += 64) {
    int i = base + lane;
    int srcn = node;
    float q0 = 0.f;
    if (i < end) {
      srcn = col_src[i];
      q0 = __expf(lrelu(s[srcn] + t0) - m0);
      dp += q0;
    }
    const int cnt = min(64, end - base);
    const int cnt4 = (cnt + 3) & ~3;
    int i0 = __shfl(srcn, 0), i1 = __shfl(srcn, 1), i2 = __shfl(srcn, 2), i3 = __shfl(srcn, 3);
    __half b0 = h16[(size_t)i0 * 64 + lane];
    __half b1 = h16[(size_t)i1 * 64 + lane];
    __half b2 = h16[(size_t)i2 * 64 + lane];
    __half b3 = h16[(size_t)i3 * 64 + lane];
    for (int j = 0; j < cnt4; j += 4) {
      float p0 = __shfl(q0, j),     p1 = __shfl(q0, j + 1);
      float p2 = __shfl(q0, j + 2), p3 = __shfl(q0, j + 3);
      float c0 = __half2float(b0), c1 = __half2float(b1);
      float c2 = __half2float(b2), c3 = __half2float(b3);
      if (j + 4 < cnt4) {
        int n0 = __shfl(srcn, j + 4), n1 = __shfl(srcn, j + 5);
        int n2 = __shfl(srcn, j + 6), n3 = __shfl(srcn, j + 7);
        b0 = h16[(size_t)n0 * 64 + lane];
        b1 = h16[(size_t)n1 * 64 + lane];
        b2 = h16[(size_t)n2 * 64 + lane];
        b3 = h16[(size_t)n3 * 64 + lane];
      }
      acc0 = fmaf(p0, c0, acc0);
      acc0 = fmaf(p1, c1, acc0);
      acc0 = fmaf(p2, c2, acc0);
      acc0 = fmaf(p3, c3, acc0);
    }
  }
#pragma unroll
  for (int off = 32; off > 0; off >>= 1) dp += __shfl_xor(dp, off);
  const float d0 = dp + p;

  float o = acc0 / (d0 + 1e-16f) + bias[lane];
  out[(size_t)node * 64 + lane] = o;
  ushort_t oh = f2bf_rn(o);
  outh[(size_t)node * 64 + lane] = oh;
  outl[(size_t)node * 64 + lane] = f2bf_rn(o - bf2f(oh));
}

extern "C" void kernel_launch(void* const* d_in, const int* in_sizes, int n_in,
                              void* d_out, int out_size, void* d_ws, size_t ws_size,
                              hipStream_t stream) {
  const float* x       = (const float*)d_in[0];
  const int*   ei      = (const int*)d_in[1];
  const float* W0      = (const float*)d_in[2];
  const float* a_src0  = (const float*)d_in[3];
  const float* a_dst0  = (const float*)d_in[4];
  const float* b0      = (const float*)d_in[5];
  const float* W1      = (const float*)d_in[6];
  const float* a_src1  = (const float*)d_in[7];
  const float* a_dst1  = (const float*)d_in[8];
  const float* b1      = (const float*)d_in[9];
  const float* W2      = (const float*)d_in[10];
  const float* a_src2  = (const float*)d_in[11];
  const float* a_dst2  = (const float*)d_in[12];
  const float* b2      = (const float*)d_in[13];
  const float* Wv      = (const float*)d_in[14];
  const float* bv      = (const float*)d_in[15];
  const float* Wt      = (const float*)d_in[16];
  const float* bt      = (const float*)d_in[17];

  const int n = NN, E = NE;
  const int NB = (n + 255) / 256;
  const int NBF = (n + 1 + 255) / 256;

  char* w = (char*)d_ws;
  int* counts  = (int*)w;   w += (size_t)n * 4;
  int* row_ptr = (int*)w;   w += (size_t)(n + 4) * 4;
  int* cursor  = (int*)w;   w += (size_t)n * 4;
  int* bsums   = (int*)w;   w += (size_t)256 * 4;
  uint_t* smax = (uint_t*)w; w += (size_t)8 * 4;
  int* col_src = (int*)w;   w += (size_t)E * 4;
  float* s_arr = (float*)w; w += (size_t)n * 2 * 4;
  float* t_arr = (float*)w; w += (size_t)n * 2 * 4;
  ushort_t* AhP = (ushort_t*)w; w += (size_t)n * 128 * 2;
  ushort_t* AlP = (ushort_t*)w; w += (size_t)n * 128 * 2;
  __half2* h2h = (__half2*)w; w += (size_t)n * 64 * 4;
  __half* h16  = (__half*)w; w += (size_t)n * 64 * 2;
  ushort_t* h64h = (ushort_t*)w; w += (size_t)n * 64 * 2;
  ushort_t* h64l = (ushort_t*)w; w += (size_t)n * 64 * 2;
  ushort_t* wt0h = (ushort_t*)w; w += (size_t)128 * 512 * 2;
  ushort_t* wt0l = (ushort_t*)w; w += (size_t)128 * 512 * 2;
  ushort_t* wt1h = (ushort_t*)w; w += (size_t)128 * 128 * 2;
  ushort_t* wt1l = (ushort_t*)w; w += (size_t)128 * 128 * 2;
  ushort_t* wt2h = (ushort_t*)w; w += (size_t)64 * 128 * 2;
  ushort_t* wt2l = (ushort_t*)w; w += (size_t)64 * 128 * 2;
  ushort_t* wHh  = (ushort_t*)w; w += (size_t)128 * 64 * 2;
  ushort_t* wHl  = (ushort_t*)w; w += (size_t)128 * 64 * 2;

  float* s1 = s_arr;
  float* t1 = t_arr;

  float* out_h = (float*)d_out;
  float* out_v = out_h + (size_t)n * 64;
  float* out_t = out_v + (size_t)n * 64;

  // ---- setup: zero(+keys) + (count + W preps) + scan + fill ----
  zero_kernel<<<NB, 256, 0, stream>>>(counts, n, smax);
  setup_kernel<<<CNT_BLOCKS + 16 + 4 + 2 + 1 + 1, 256, 0, stream>>>(
      ei, counts, W0, wt0h, wt0l, W1, wt1h, wt1l, W2, wt2h, wt2l, Wv, Wt, wHh, wHl);
  scan_blocksum_kernel<<<NB, 256, 0, stream>>>(counts, bsums, n);
  scan_offsets_kernel<<<1, 256, 0, stream>>>(bsums, NB);
  scan_final_kernel<<<NBF, 256, 0, stream>>>(counts, bsums, row_ptr, cursor, n, E);
  fill_kernel<<<(E + 255) / 256, 256, 0, stream>>>(ei, row_ptr, cursor, col_src, E);

  const int wgrid = (n + 3) / 4;
  const int g64 = (n + 63) / 64;   // 782 blocks

  // ---- layer 0 ----
  gemm_att128_kernel<512, false><<<g64, 256, 0, stream>>>(x, nullptr, nullptr, wt0h, wt0l,
                                                          a_src0, a_dst0, h2h, s_arr, t_arr,
                                                          smax + 0, n);
  agg2_kernel<<<wgrid, 256, 0, stream>>>(h2h, (const float2*)s_arr, (const float2*)t_arr,
                                         row_ptr, col_src, b0, smax + 0, AhP, AlP, n);

  // ---- layer 1 ----
  gemm_att128_kernel<128, true><<<g64, 256, 0, stream>>>(nullptr, AhP, AlP, wt1h, wt1l,
                                                         a_src1, a_dst1, h2h, s_arr, t_arr,
                                                         smax + 2, n);
  agg2_kernel<<<wgrid, 256, 0, stream>>>(h2h, (const float2*)s_arr, (const float2*)t_arr,
                                         row_ptr, col_src, b1, smax + 2, AhP, AlP, n);

  // ---- layer 2 ----
  gemm_att64_kernel<<<g64, 256, 0, stream>>>(AhP, AlP, wt2h, wt2l, a_src2, a_dst2,
                                             h16, s1, t1, smax + 4, n);
  agg1_kernel<<<wgrid, 256, 0, stream>>>(h16, s1, t1, row_ptr, col_src, b2, smax + 4,
                                         out_h, h64h, h64l, n);

  // ---- both MLP heads ----
  gemm_heads_kernel<<<g64, 256, 0, stream>>>(h64h, h64l, wHh, wHl, bv, bt, out_v, out_t, n);
}

// Round 15
// 300.524 us; speedup vs baseline: 1.3025x; 1.3025x over previous
//
#include <hip/hip_runtime.h>
#include <hip/hip_bf16.h>
#include <hip/hip_fp16.h>
#include <math.h>

#define NN 50000
#define NE 800000

typedef unsigned short ushort_t;
typedef unsigned int uint_t;
typedef __attribute__((ext_vector_type(8))) short bf16x8;
typedef __attribute__((ext_vector_type(4))) float f32x4;

__device__ __forceinline__ float lrelu(float x) { return x >= 0.f ? x : 0.2f * x; }

__device__ __forceinline__ ushort_t f2bf_rn(float f) {
  uint_t u = __builtin_bit_cast(uint_t, f);
  uint_t r = u + 0x7FFFu + ((u >> 16) & 1u);
  return (ushort_t)(r >> 16);
}
__device__ __forceinline__ float bf2f(ushort_t h) {
  uint_t u = ((uint_t)h) << 16;
  return __builtin_bit_cast(float, u);
}
__device__ __forceinline__ ushort_t f2h_bits(float f) {
  __half h = __float2half(f);
  return __builtin_bit_cast(ushort_t, h);
}

// ---------------- zero counts ----------------
__global__ __launch_bounds__(256) void zero_kernel(int* __restrict__ p, int n) {
  int i = blockIdx.x * 256 + threadIdx.x;
  if (i < n) p[i] = 0;
}

// ---------------- W prep: transpose + bf16 hi/lo split. W[K][C] -> wt[C][K] ----------------
__device__ __forceinline__ void prep_dev(const float* __restrict__ W, int Kdim, int C,
                                         ushort_t* __restrict__ wth, ushort_t* __restrict__ wtl,
                                         int t) {
  int nk = Kdim >> 4;
  if (t >= C * nk) return;
  int c = t / nk, kc = (t % nk) << 4;
  uint_t hw[8], lw[8];
#pragma unroll
  for (int i = 0; i < 8; ++i) {
    float f0 = W[(size_t)(kc + 2 * i) * C + c];
    float f1 = W[(size_t)(kc + 2 * i + 1) * C + c];
    ushort_t h0 = f2bf_rn(f0), h1 = f2bf_rn(f1);
    ushort_t l0 = f2bf_rn(f0 - bf2f(h0)), l1 = f2bf_rn(f1 - bf2f(h1));
    hw[i] = (uint_t)h0 | ((uint_t)h1 << 16);
    lw[i] = (uint_t)l0 | ((uint_t)l1 << 16);
  }
  uint_t* ph = (uint_t*)&wth[(size_t)c * Kdim + kc];
  uint_t* pl = (uint_t*)&wtl[(size_t)c * Kdim + kc];
  *(uint4*)ph = make_uint4(hw[0], hw[1], hw[2], hw[3]);
  *(uint4*)(ph + 4) = make_uint4(hw[4], hw[5], hw[6], hw[7]);
  *(uint4*)pl = make_uint4(lw[0], lw[1], lw[2], lw[3]);
  *(uint4*)(pl + 4) = make_uint4(lw[4], lw[5], lw[6], lw[7]);
}

// ---------------- setup: edge count + all W preps (block-specialized) ----------------
#define CNT_BLOCKS 3125
__global__ __launch_bounds__(256) void setup_kernel(const int* __restrict__ ei,
                                                    int* __restrict__ counts,
                                                    const float* __restrict__ W0, ushort_t* wt0h, ushort_t* wt0l,
                                                    const float* __restrict__ W1, ushort_t* wt1h, ushort_t* wt1l,
                                                    const float* __restrict__ W2, ushort_t* wt2h, ushort_t* wt2l,
                                                    const float* __restrict__ Wv, const float* __restrict__ Wt,
                                                    ushort_t* wHh, ushort_t* wHl) {
  int b = blockIdx.x;
  if (b < CNT_BLOCKS) {
    int e = b * 256 + threadIdx.x;
    if (e < NE) atomicAdd(&counts[ei[NE + e]], 1);
    return;
  }
  b -= CNT_BLOCKS;
  if (b < 16) { prep_dev(W0, 512, 128, wt0h, wt0l, b * 256 + threadIdx.x); return; }
  b -= 16;
  if (b < 4) { prep_dev(W1, 128, 128, wt1h, wt1l, b * 256 + threadIdx.x); return; }
  b -= 4;
  if (b < 2) { prep_dev(W2, 128, 64, wt2h, wt2l, b * 256 + threadIdx.x); return; }
  b -= 2;
  if (b < 1) { prep_dev(Wv, 64, 64, wHh, wHl, b * 256 + threadIdx.x); return; }
  b -= 1;
  prep_dev(Wt, 64, 64, wHh + 64 * 64, wHl + 64 * 64, b * 256 + threadIdx.x);
}

// ---------------- hierarchical scan ----------------
__global__ __launch_bounds__(256) void scan_blocksum_kernel(const int* __restrict__ counts,
                                                            int* __restrict__ bsums, int n) {
  __shared__ int red[4];
  int i = blockIdx.x * 256 + threadIdx.x;
  int v = (i < n) ? counts[i] : 0;
#pragma unroll
  for (int off = 32; off > 0; off >>= 1) v += __shfl_down(v, off);
  if ((threadIdx.x & 63) == 0) red[threadIdx.x >> 6] = v;
  __syncthreads();
  if (threadIdx.x == 0) bsums[blockIdx.x] = red[0] + red[1] + red[2] + red[3];
}

__global__ __launch_bounds__(256) void scan_offsets_kernel(int* __restrict__ bsums, int nb) {
  __shared__ int sm[256];
  int tid = threadIdx.x;
  int v = (tid < nb) ? bsums[tid] : 0;
  sm[tid] = v;
  __syncthreads();
  for (int off = 1; off < 256; off <<= 1) {
    int u = (tid >= off) ? sm[tid - off] : 0;
    __syncthreads();
    sm[tid] += u;
    __syncthreads();
  }
  if (tid < nb) bsums[tid] = sm[tid] - v;  // exclusive
}

__global__ __launch_bounds__(256) void scan_final_kernel(const int* __restrict__ counts,
                                                         const int* __restrict__ boffs,
                                                         int* __restrict__ row_ptr,
                                                         int* __restrict__ cursor, int n, int E) {
  __shared__ int sm[256];
  int tid = threadIdx.x;
  int i = blockIdx.x * 256 + tid;
  int v = (i < n) ? counts[i] : 0;
  int orig = v;
  sm[tid] = v;
  __syncthreads();
  for (int off = 1; off < 256; off <<= 1) {
    int u = (tid >= off) ? sm[tid - off] : 0;
    __syncthreads();
    sm[tid] += u;
    __syncthreads();
  }
  if (i < n) {
    row_ptr[i] = boffs[blockIdx.x] + sm[tid] - orig;
    cursor[i] = 0;
  }
  if (i == n) row_ptr[n] = E;
}

__global__ void fill_kernel(const int* __restrict__ ei, const int* __restrict__ row_ptr,
                            int* __restrict__ cursor, int* __restrict__ col_src, int E) {
  int e = blockIdx.x * blockDim.x + threadIdx.x;
  if (e < E) {
    int d = ei[E + e];
    int pos = row_ptr[d] + atomicAdd(&cursor[d], 1);
    col_src[pos] = ei[e];
  }
}

// ---------------- MFMA GEMM 64x128 tile + fused att2 epilogue ----------------
// Stride 40 ushorts = 80 B (multiple of 16): every ds_read_b128/ds_write_b128 aligned.
// Frag-read bank starts (20*r16)%32 -> 8 positions x 4 banks = 2 lanes/bank (free, m136).
template <int K, bool SPLIT>
__global__ __launch_bounds__(256, 4) void gemm_att128_kernel(const float* __restrict__ Af,
                                                             const ushort_t* __restrict__ Ahp,
                                                             const ushort_t* __restrict__ Alp,
                                                             const ushort_t* __restrict__ wth,
                                                             const ushort_t* __restrict__ wtl,
                                                             const float* __restrict__ a_src,
                                                             const float* __restrict__ a_dst,
                                                             __half2* __restrict__ h2h,
                                                             float* __restrict__ s_arr,
                                                             float* __restrict__ t_arr, int n) {
  __shared__ __align__(16) ushort_t smem[15360];  // 30.7 KB
  ushort_t (*ah)[40] = (ushort_t(*)[40])smem;                 // [64][40]
  ushort_t (*al)[40] = (ushort_t(*)[40])(smem + 2560);        // [64][40]
  ushort_t (*bh)[40] = (ushort_t(*)[40])(smem + 5120);        // [128][40]
  ushort_t (*bl)[40] = (ushort_t(*)[40])(smem + 10240);       // [128][40]

  const int t = threadIdx.x;
  const int row0 = blockIdx.x * 64;
  const int asrow = t >> 2, akc = (t & 3) * 8;
  const int bcol = t >> 1, bkc = (t & 1) * 16;

  const int lane = t & 63;
  const int wid = t >> 6;
  const int wm = wid >> 1, wn = wid & 1;   // wave: rows wm*32..+31, cols wn*64..+63
  const int r16 = lane & 15, g = lane >> 4;

  f32x4 acc[2][4];
#pragma unroll
  for (int i = 0; i < 2; ++i)
#pragma unroll
    for (int j = 0; j < 4; ++j) acc[i][j] = (f32x4)(0.f);

  for (int kt = 0; kt < K / 32; ++kt) {
    const int k0 = kt * 32;
    // ---- stage A ----
    if (SPLIT) {
      uint4 vh = make_uint4(0, 0, 0, 0), vl = vh;
      if (row0 + asrow < n) {
        vh = *(const uint4*)&Ahp[(size_t)(row0 + asrow) * K + k0 + akc];
        vl = *(const uint4*)&Alp[(size_t)(row0 + asrow) * K + k0 + akc];
      }
      *(uint4*)&ah[asrow][akc] = vh;
      *(uint4*)&al[asrow][akc] = vl;
    } else {
      uint_t hw[4], lw[4];
      if (row0 + asrow < n) {
        const float* ap = &Af[(size_t)(row0 + asrow) * K + k0 + akc];
#pragma unroll
        for (int j = 0; j < 2; ++j) {
          float4 v = *(const float4*)(ap + j * 4);
          ushort_t h0 = f2bf_rn(v.x), h1 = f2bf_rn(v.y), h2 = f2bf_rn(v.z), h3 = f2bf_rn(v.w);
          ushort_t l0 = f2bf_rn(v.x - bf2f(h0)), l1 = f2bf_rn(v.y - bf2f(h1));
          ushort_t l2 = f2bf_rn(v.z - bf2f(h2)), l3 = f2bf_rn(v.w - bf2f(h3));
          hw[j * 2] = (uint_t)h0 | ((uint_t)h1 << 16);
          hw[j * 2 + 1] = (uint_t)h2 | ((uint_t)h3 << 16);
          lw[j * 2] = (uint_t)l0 | ((uint_t)l1 << 16);
          lw[j * 2 + 1] = (uint_t)l2 | ((uint_t)l3 << 16);
        }
      } else {
#pragma unroll
        for (int j = 0; j < 4; ++j) { hw[j] = 0; lw[j] = 0; }
      }
      *(uint4*)&ah[asrow][akc] = make_uint4(hw[0], hw[1], hw[2], hw[3]);
      *(uint4*)&al[asrow][akc] = make_uint4(lw[0], lw[1], lw[2], lw[3]);
    }
    // ---- stage B (pre-split planes [128][K]) ----
    {
      const ushort_t* ph = &wth[(size_t)bcol * K + k0 + bkc];
      const ushort_t* pl = &wtl[(size_t)bcol * K + k0 + bkc];
      *(uint4*)&bh[bcol][bkc] = *(const uint4*)ph;
      *(uint4*)&bh[bcol][bkc + 8] = *(const uint4*)(ph + 8);
      *(uint4*)&bl[bcol][bkc] = *(const uint4*)pl;
      *(uint4*)&bl[bcol][bkc + 8] = *(const uint4*)(pl + 8);
    }
    __syncthreads();

    bf16x8 fah[2], fal[2], fbh[4], fbl[4];
#pragma unroll
    for (int mf = 0; mf < 2; ++mf) {
      fah[mf] = *(const bf16x8*)&ah[wm * 32 + mf * 16 + r16][g * 8];
      fal[mf] = *(const bf16x8*)&al[wm * 32 + mf * 16 + r16][g * 8];
    }
#pragma unroll
    for (int nf = 0; nf < 4; ++nf) {
      fbh[nf] = *(const bf16x8*)&bh[wn * 64 + nf * 16 + r16][g * 8];
      fbl[nf] = *(const bf16x8*)&bl[wn * 64 + nf * 16 + r16][g * 8];
    }
#pragma unroll
    for (int mf = 0; mf < 2; ++mf)
#pragma unroll
      for (int nf = 0; nf < 4; ++nf) {
        acc[mf][nf] = __builtin_amdgcn_mfma_f32_16x16x32_bf16(fah[mf], fbh[nf], acc[mf][nf], 0, 0, 0);
        acc[mf][nf] = __builtin_amdgcn_mfma_f32_16x16x32_bf16(fah[mf], fbl[nf], acc[mf][nf], 0, 0, 0);
        acc[mf][nf] = __builtin_amdgcn_mfma_f32_16x16x32_bf16(fal[mf], fbh[nf], acc[mf][nf], 0, 0, 0);
      }
    __syncthreads();
  }

  // ---- fused att epilogue: s,t (wave owns head wn, full 64 cols) ----
  const int head = wn;
  float asv[4], adv[4];
#pragma unroll
  for (int nf = 0; nf < 4; ++nf) {
    asv[nf] = a_src[head * 64 + nf * 16 + r16];
    adv[nf] = a_dst[head * 64 + nf * 16 + r16];
  }
#pragma unroll
  for (int mf = 0; mf < 2; ++mf) {
#pragma unroll
    for (int reg = 0; reg < 4; ++reg) {
      float sp = 0.f, tp = 0.f;
#pragma unroll
      for (int nf = 0; nf < 4; ++nf) {
        sp = fmaf(acc[mf][nf][reg], asv[nf], sp);
        tp = fmaf(acc[mf][nf][reg], adv[nf], tp);
      }
#pragma unroll
      for (int off = 1; off < 16; off <<= 1) {
        sp += __shfl_xor(sp, off);
        tp += __shfl_xor(tp, off);
      }
      int row = row0 + wm * 32 + mf * 16 + g * 4 + reg;
      if (r16 == 0 && row < n) {
        s_arr[row * 2 + head] = sp;
        t_arr[row * 2 + head] = tp;
      }
    }
  }

  // ---- f16 repack via LDS, coalesced h2h store (interleaved heads) ----
  ushort_t* hstage = smem;  // [64][136], 272 B stride (16-aligned)
#pragma unroll
  for (int mf = 0; mf < 2; ++mf)
#pragma unroll
    for (int nf = 0; nf < 4; ++nf)
#pragma unroll
      for (int reg = 0; reg < 4; ++reg) {
        int rl = wm * 32 + mf * 16 + g * 4 + reg;
        int col = (nf * 16 + r16) * 2 + head;
        hstage[rl * 136 + col] = f2h_bits(acc[mf][nf][reg]);
      }
  __syncthreads();
#pragma unroll
  for (int it = 0; it < 4; ++it) {
    int idx = t + it * 256;
    int r = idx >> 4, ch = idx & 15;  // 16 chunks of 16B per 256B row
    if (row0 + r < n) {
      *(uint4*)((char*)h2h + (size_t)(row0 + r) * 256 + ch * 16) =
          *(const uint4*)&hstage[r * 136 + ch * 8];
    }
  }
}

// ---------------- MFMA GEMM 64x64 + fused att1 (layer 2, K=128, pre-split A) ----------------
__global__ __launch_bounds__(256, 4) void gemm_att64_kernel(const ushort_t* __restrict__ Ahp,
                                                            const ushort_t* __restrict__ Alp,
                                                            const ushort_t* __restrict__ wth,
                                                            const ushort_t* __restrict__ wtl,
                                                            const float* __restrict__ a_src,
                                                            const float* __restrict__ a_dst,
                                                            __half* __restrict__ h16,
                                                            float* __restrict__ s1,
                                                            float* __restrict__ t1, int n) {
  constexpr int K = 128;
  __shared__ __align__(16) ushort_t smem[10240];  // 20.5 KB
  ushort_t (*ah)[40] = (ushort_t(*)[40])smem;
  ushort_t (*al)[40] = (ushort_t(*)[40])(smem + 2560);
  ushort_t (*bh)[40] = (ushort_t(*)[40])(smem + 5120);
  ushort_t (*bl)[40] = (ushort_t(*)[40])(smem + 7680);

  const int t = threadIdx.x;
  const int row0 = blockIdx.x * 64;
  const int asrow = t >> 2, akc = (t & 3) * 8;
  const bool arow_ok = (row0 + asrow) < n;

  const int lane = t & 63;
  const int wid = t >> 6;
  const int r16 = lane & 15, g = lane >> 4;

  f32x4 acc[4];
#pragma unroll
  for (int j = 0; j < 4; ++j) acc[j] = (f32x4)(0.f);

  for (int kt = 0; kt < K / 32; ++kt) {
    const int k0 = kt * 32;
    {
      uint4 vh = make_uint4(0, 0, 0, 0), vl = vh;
      if (arow_ok) {
        vh = *(const uint4*)&Ahp[(size_t)(row0 + asrow) * K + k0 + akc];
        vl = *(const uint4*)&Alp[(size_t)(row0 + asrow) * K + k0 + akc];
      }
      *(uint4*)&ah[asrow][akc] = vh;
      *(uint4*)&al[asrow][akc] = vl;
    }
    {
      *(uint4*)&bh[asrow][akc] = *(const uint4*)&wth[(size_t)asrow * K + k0 + akc];
      *(uint4*)&bl[asrow][akc] = *(const uint4*)&wtl[(size_t)asrow * K + k0 + akc];
    }
    __syncthreads();

    bf16x8 fahv, falv, fbh[4], fbl[4];
    fahv = *(const bf16x8*)&ah[wid * 16 + r16][g * 8];
    falv = *(const bf16x8*)&al[wid * 16 + r16][g * 8];
#pragma unroll
    for (int nf = 0; nf < 4; ++nf) {
      fbh[nf] = *(const bf16x8*)&bh[nf * 16 + r16][g * 8];
      fbl[nf] = *(const bf16x8*)&bl[nf * 16 + r16][g * 8];
    }
#pragma unroll
    for (int nf = 0; nf < 4; ++nf) {
      acc[nf] = __builtin_amdgcn_mfma_f32_16x16x32_bf16(fahv, fbh[nf], acc[nf], 0, 0, 0);
      acc[nf] = __builtin_amdgcn_mfma_f32_16x16x32_bf16(fahv, fbl[nf], acc[nf], 0, 0, 0);
      acc[nf] = __builtin_amdgcn_mfma_f32_16x16x32_bf16(falv, fbh[nf], acc[nf], 0, 0, 0);
    }
    __syncthreads();
  }

  // ---- fused att1 epilogue ----
  float asv[4], adv[4];
#pragma unroll
  for (int nf = 0; nf < 4; ++nf) {
    asv[nf] = a_src[nf * 16 + r16];
    adv[nf] = a_dst[nf * 16 + r16];
  }
#pragma unroll
  for (int reg = 0; reg < 4; ++reg) {
    float sp = 0.f, tp = 0.f;
#pragma unroll
    for (int nf = 0; nf < 4; ++nf) {
      sp = fmaf(acc[nf][reg], asv[nf], sp);
      tp = fmaf(acc[nf][reg], adv[nf], tp);
    }
#pragma unroll
    for (int off = 1; off < 16; off <<= 1) {
      sp += __shfl_xor(sp, off);
      tp += __shfl_xor(tp, off);
    }
    int row = row0 + wid * 16 + g * 4 + reg;
    if (r16 == 0 && row < n) {
      s1[row] = sp;
      t1[row] = tp;
    }
  }

  // ---- f16 repack + coalesced store ----
  ushort_t* hstage = smem;  // [64][72], 144 B stride (16-aligned)
#pragma unroll
  for (int nf = 0; nf < 4; ++nf)
#pragma unroll
    for (int reg = 0; reg < 4; ++reg) {
      int rl = wid * 16 + g * 4 + reg;
      hstage[rl * 72 + nf * 16 + r16] = f2h_bits(acc[nf][reg]);
    }
  __syncthreads();
#pragma unroll
  for (int it = 0; it < 2; ++it) {
    int idx = t + it * 256;
    int r = idx >> 3, ch = idx & 7;  // 8 chunks of 16B per 128B row
    if (row0 + r < n) {
      *(uint4*)((char*)h16 + (size_t)(row0 + r) * 128 + ch * 16) =
          *(const uint4*)&hstage[r * 72 + ch * 8];
    }
  }
}

// ---------------- MFMA GEMM 64x128: both MLP heads, K=64, pre-split A ----------------
__global__ __launch_bounds__(256, 4) void gemm_heads_kernel(const ushort_t* __restrict__ Ahp,
                                                            const ushort_t* __restrict__ Alp,
                                                            const ushort_t* __restrict__ wth,
                                                            const ushort_t* __restrict__ wtl,
                                                            const float* __restrict__ bv,
                                                            const float* __restrict__ bt,
                                                            float* __restrict__ out_v,
                                                            float* __restrict__ out_t, int n) {
  constexpr int K = 64;
  __shared__ __align__(16) ushort_t smem[15360];
  ushort_t (*ah)[40] = (ushort_t(*)[40])smem;
  ushort_t (*al)[40] = (ushort_t(*)[40])(smem + 2560);
  ushort_t (*bh)[40] = (ushort_t(*)[40])(smem + 5120);
  ushort_t (*bl)[40] = (ushort_t(*)[40])(smem + 10240);

  const int t = threadIdx.x;
  const int row0 = blockIdx.x * 64;
  const int asrow = t >> 2, akc = (t & 3) * 8;
  const int bcol = t >> 1, bkc = (t & 1) * 16;
  const bool arow_ok = (row0 + asrow) < n;

  const int lane = t & 63;
  const int wid = t >> 6;
  const int wm = wid >> 1, wn = wid & 1;
  const int r16 = lane & 15, g = lane >> 4;

  f32x4 acc[2][4];
#pragma unroll
  for (int i = 0; i < 2; ++i)
#pragma unroll
    for (int j = 0; j < 4; ++j) acc[i][j] = (f32x4)(0.f);

  for (int kt = 0; kt < K / 32; ++kt) {
    const int k0 = kt * 32;
    {
      uint4 vh = make_uint4(0, 0, 0, 0), vl = vh;
      if (arow_ok) {
        vh = *(const uint4*)&Ahp[(size_t)(row0 + asrow) * K + k0 + akc];
        vl = *(const uint4*)&Alp[(size_t)(row0 + asrow) * K + k0 + akc];
      }
      *(uint4*)&ah[asrow][akc] = vh;
      *(uint4*)&al[asrow][akc] = vl;
    }
    {
      const ushort_t* ph = &wth[(size_t)bcol * K + k0 + bkc];
      const ushort_t* pl = &wtl[(size_t)bcol * K + k0 + bkc];
      *(uint4*)&bh[bcol][bkc] = *(const uint4*)ph;
      *(uint4*)&bh[bcol][bkc + 8] = *(const uint4*)(ph + 8);
      *(uint4*)&bl[bcol][bkc] = *(const uint4*)pl;
      *(uint4*)&bl[bcol][bkc + 8] = *(const uint4*)(pl + 8);
    }
    __syncthreads();

    bf16x8 fah[2], fal[2], fbh[4], fbl[4];
#pragma unroll
    for (int mf = 0; mf < 2; ++mf) {
      fah[mf] = *(const bf16x8*)&ah[wm * 32 + mf * 16 + r16][g * 8];
      fal[mf] = *(const bf16x8*)&al[wm * 32 + mf * 16 + r16][g * 8];
    }
#pragma unroll
    for (int nf = 0; nf < 4; ++nf) {
      fbh[nf] = *(const bf16x8*)&bh[wn * 64 + nf * 16 + r16][g * 8];
      fbl[nf] = *(const bf16x8*)&bl[wn * 64 + nf * 16 + r16][g * 8];
    }
#pragma unroll
    for (int mf = 0; mf < 2; ++mf)
#pragma unroll
      for (int nf = 0; nf < 4; ++nf) {
        acc[mf][nf] = __builtin_amdgcn_mfma_f32_16x16x32_bf16(fah[mf], fbh[nf], acc[mf][nf], 0, 0, 0);
        acc[mf][nf] = __builtin_amdgcn_mfma_f32_16x16x32_bf16(fah[mf], fbl[nf], acc[mf][nf], 0, 0, 0);
        acc[mf][nf] = __builtin_amdgcn_mfma_f32_16x16x32_bf16(fal[mf], fbh[nf], acc[mf][nf], 0, 0, 0);
      }
    __syncthreads();
  }

  const float* bias = wn ? bt : bv;
  float* outp = wn ? out_t : out_v;
#pragma unroll
  for (int mf = 0; mf < 2; ++mf) {
#pragma unroll
    for (int reg = 0; reg < 4; ++reg) {
      int row = row0 + wm * 32 + mf * 16 + g * 4 + reg;
      if (row < n) {
#pragma unroll
        for (int nf = 0; nf < 4; ++nf) {
          int c = nf * 16 + r16;
          outp[(size_t)row * 64 + c] = fmaxf(acc[mf][nf][reg] + bias[c], 0.f);
        }
      }
    }
  }
}

// ---------------- two-pass softmax aggregation, H=2, f16 gathers -> bf16-split planes ----------------
__global__ __launch_bounds__(256) void agg2_kernel(const __half2* __restrict__ h2h,
                                                   const float2* __restrict__ s2,
                                                   const float2* __restrict__ t2,
                                                   const int* __restrict__ row_ptr,
                                                   const int* __restrict__ col_src,
                                                   const float* __restrict__ bias,
                                                   ushort_t* __restrict__ outh,
                                                   ushort_t* __restrict__ outl, int n) {
  int wid = (blockIdx.x * 256 + threadIdx.x) >> 6;
  int lane = threadIdx.x & 63;
  if (wid >= n) return;
  const int node = wid;
  const float2 tt = t2[node];
  const float t0 = tt.x, t1 = tt.y;
  const int beg = row_ptr[node], end = row_ptr[node + 1];

  float2 sself = s2[node];
  const float e_self0 = lrelu(sself.x + t0);
  const float e_self1 = lrelu(sself.y + t1);

  const int i_own = beg + lane;
  int src_own = node;
  float e0_own = -1e30f, e1_own = -1e30f;
  if (i_own < end) {
    src_own = col_src[i_own];
    float2 sv = s2[src_own];
    e0_own = lrelu(sv.x + t0);
    e1_own = lrelu(sv.y + t1);
  }
  float m0 = fmaxf(e_self0, e0_own), m1 = fmaxf(e_self1, e1_own);
  for (int i = beg + 64 + lane; i < end; i += 64) {
    float2 sv = s2[col_src[i]];
    m0 = fmaxf(m0, lrelu(sv.x + t0));
    m1 = fmaxf(m1, lrelu(sv.y + t1));
  }
#pragma unroll
  for (int off = 32; off > 0; off >>= 1) {
    m0 = fmaxf(m0, __shfl_xor(m0, off));
    m1 = fmaxf(m1, __shfl_xor(m1, off));
  }

  float p0 = __expf(e_self0 - m0);
  float p1 = __expf(e_self1 - m1);
  float d0 = p0, d1 = p1;
  float2 hself = __half22float2(h2h[(size_t)node * 64 + lane]);
  float acc0 = p0 * hself.x;
  float acc1 = p1 * hself.y;

  for (int base = beg; base < end; base += 64) {
    int srcn;
    float q0, q1;
    if (base == beg) {
      srcn = src_own;
      q0 = (i_own < end) ? __expf(e0_own - m0) : 0.f;
      q1 = (i_own < end) ? __expf(e1_own - m1) : 0.f;
    } else {
      int i = base + lane;
      srcn = node;
      q0 = 0.f; q1 = 0.f;
      if (i < end) {
        srcn = col_src[i];
        float2 sv = s2[srcn];
        q0 = __expf(lrelu(sv.x + t0) - m0);
        q1 = __expf(lrelu(sv.y + t1) - m1);
      }
    }
    const int cnt = min(64, end - base);
    const int cnt4 = (cnt + 3) & ~3;
    int i0 = __shfl(srcn, 0), i1 = __shfl(srcn, 1), i2 = __shfl(srcn, 2), i3 = __shfl(srcn, 3);
    __half2 b0 = h2h[(size_t)i0 * 64 + lane];
    __half2 b1 = h2h[(size_t)i1 * 64 + lane];
    __half2 b2 = h2h[(size_t)i2 * 64 + lane];
    __half2 b3 = h2h[(size_t)i3 * 64 + lane];
    for (int j = 0; j < cnt4; j += 4) {
      float p00 = __shfl(q0, j),     p01 = __shfl(q1, j);
      float p10 = __shfl(q0, j + 1), p11 = __shfl(q1, j + 1);
      float p20 = __shfl(q0, j + 2), p21 = __shfl(q1, j + 2);
      float p30 = __shfl(q0, j + 3), p31 = __shfl(q1, j + 3);
      __half2 c0 = b0, c1 = b1, c2 = b2, c3 = b3;
      if (j + 4 < cnt4) {
        int n0 = __shfl(srcn, j + 4), n1 = __shfl(srcn, j + 5);
        int n2 = __shfl(srcn, j + 6), n3 = __shfl(srcn, j + 7);
        b0 = h2h[(size_t)n0 * 64 + lane];
        b1 = h2h[(size_t)n1 * 64 + lane];
        b2 = h2h[(size_t)n2 * 64 + lane];
        b3 = h2h[(size_t)n3 * 64 + lane];
      }
      float2 f0 = __half22float2(c0), f1 = __half22float2(c1);
      float2 f2 = __half22float2(c2), f3 = __half22float2(c3);
      d0 += p00 + p10 + p20 + p30;
      d1 += p01 + p11 + p21 + p31;
      acc0 = fmaf(p00, f0.x, acc0);
      acc1 = fmaf(p01, f0.y, acc1);
      acc0 = fmaf(p10, f1.x, acc0);
      acc1 = fmaf(p11, f1.y, acc1);
      acc0 = fmaf(p20, f2.x, acc0);
      acc1 = fmaf(p21, f2.y, acc1);
      acc0 = fmaf(p30, f3.x, acc0);
      acc1 = fmaf(p31, f3.y, acc1);
    }
  }

  float o0 = fmaxf(acc0 / (d0 + 1e-16f) + bias[lane], 0.f);        // relu fused
  float o1 = fmaxf(acc1 / (d1 + 1e-16f) + bias[64 + lane], 0.f);
  ushort_t h0h = f2bf_rn(o0), h1h = f2bf_rn(o1);
  outh[(size_t)node * 128 + lane] = h0h;
  outh[(size_t)node * 128 + 64 + lane] = h1h;
  outl[(size_t)node * 128 + lane] = f2bf_rn(o0 - bf2f(h0h));
  outl[(size_t)node * 128 + 64 + lane] = f2bf_rn(o1 - bf2f(h1h));
}

// ---------------- two-pass softmax aggregation, H=1 -> f32 out + bf16-split planes ----------------
__global__ __launch_bounds__(256) void agg1_kernel(const __half* __restrict__ h16,
                                                   const float* __restrict__ s,
                                                   const float* __restrict__ t,
                                                   const int* __restrict__ row_ptr,
                                                   const int* __restrict__ col_src,
                                                   const float* __restrict__ bias,
                                                   float* __restrict__ out,
                                                   ushort_t* __restrict__ outh,
                                                   ushort_t* __restrict__ outl, int n) {
  int wid = (blockIdx.x * 256 + threadIdx.x) >> 6;
  int lane = threadIdx.x & 63;
  if (wid >= n) return;
  const int node = wid;
  const float t0 = t[node];
  const int beg = row_ptr[node], end = row_ptr[node + 1];

  const float e_self = lrelu(s[node] + t0);
  const int i_own = beg + lane;
  int src_own = node;
  float e_own = -1e30f;
  if (i_own < end) {
    src_own = col_src[i_own];
    e_own = lrelu(s[src_own] + t0);
  }
  float m0 = fmaxf(e_self, e_own);
  for (int i = beg + 64 + lane; i < end; i += 64) {
    m0 = fmaxf(m0, lrelu(s[col_src[i]] + t0));
  }
#pragma unroll
  for (int off = 32; off > 0; off >>= 1) m0 = fmaxf(m0, __shfl_xor(m0, off));

  float p = __expf(e_self - m0);
  float d0 = p;
  float acc0 = p * __half2float(h16[(size_t)node * 64 + lane]);

  for (int base = beg; base < end; base += 64) {
    int srcn;
    float q0;
    if (base == beg) {
      srcn = src_own;
      q0 = (i_own < end) ? __expf(e_own - m0) : 0.f;
    } else {
      int i = base + lane;
      srcn = node;
      q0 = 0.f;
      if (i < end) {
        srcn = col_src[i];
        q0 = __expf(lrelu(s[srcn] + t0) - m0);
      }
    }
    const int cnt = min(64, end - base);
    const int cnt4 = (cnt + 3) & ~3;
    int i0 = __shfl(srcn, 0), i1 = __shfl(srcn, 1), i2 = __shfl(srcn, 2), i3 = __shfl(srcn, 3);
    __half b0 = h16[(size_t)i0 * 64 + lane];
    __half b1 = h16[(size_t)i1 * 64 + lane];
    __half b2 = h16[(size_t)i2 * 64 + lane];
    __half b3 = h16[(size_t)i3 * 64 + lane];
    for (int j = 0; j < cnt4; j += 4) {
      float p0 = __shfl(q0, j),     p1 = __shfl(q0, j + 1);
      float p2 = __shfl(q0, j + 2), p3 = __shfl(q0, j + 3);
      float c0 = __half2float(b0), c1 = __half2float(b1);
      float c2 = __half2float(b2), c3 = __half2float(b3);
      if (j + 4 < cnt4) {
        int n0 = __shfl(srcn, j + 4), n1 = __shfl(srcn, j + 5);
        int n2 = __shfl(srcn, j + 6), n3 = __shfl(srcn, j + 7);
        b0 = h16[(size_t)n0 * 64 + lane];
        b1 = h16[(size_t)n1 * 64 + lane];
        b2 = h16[(size_t)n2 * 64 + lane];
        b3 = h16[(size_t)n3 * 64 + lane];
      }
      d0 += p0 + p1 + p2 + p3;
      acc0 = fmaf(p0, c0, acc0);
      acc0 = fmaf(p1, c1, acc0);
      acc0 = fmaf(p2, c2, acc0);
      acc0 = fmaf(p3, c3, acc0);
    }
  }
  float o = acc0 / (d0 + 1e-16f) + bias[lane];
  out[(size_t)node * 64 + lane] = o;
  ushort_t oh = f2bf_rn(o);
  outh[(size_t)node * 64 + lane] = oh;
  outl[(size_t)node * 64 + lane] = f2bf_rn(o - bf2f(oh));
}

extern "C" void kernel_launch(void* const* d_in, const int* in_sizes, int n_in,
                              void* d_out, int out_size, void* d_ws, size_t ws_size,
                              hipStream_t stream) {
  const float* x       = (const float*)d_in[0];
  const int*   ei      = (const int*)d_in[1];
  const float* W0      = (const float*)d_in[2];
  const float* a_src0  = (const float*)d_in[3];
  const float* a_dst0  = (const float*)d_in[4];
  const float* b0      = (const float*)d_in[5];
  const float* W1      = (const float*)d_in[6];
  const float* a_src1  = (const float*)d_in[7];
  const float* a_dst1  = (const float*)d_in[8];
  const float* b1      = (const float*)d_in[9];
  const float* W2      = (const float*)d_in[10];
  const float* a_src2  = (const float*)d_in[11];
  const float* a_dst2  = (const float*)d_in[12];
  const float* b2      = (const float*)d_in[13];
  const float* Wv      = (const float*)d_in[14];
  const float* bv      = (const float*)d_in[15];
  const float* Wt      = (const float*)d_in[16];
  const float* bt      = (const float*)d_in[17];

  const int n = NN, E = NE;
  const int NB = (n + 255) / 256;
  const int NBF = (n + 1 + 255) / 256;

  char* w = (char*)d_ws;
  int* counts  = (int*)w;   w += (size_t)n * 4;
  int* row_ptr = (int*)w;   w += (size_t)(n + 4) * 4;
  int* cursor  = (int*)w;   w += (size_t)n * 4;
  int* bsums   = (int*)w;   w += (size_t)256 * 4;
  int* col_src = (int*)w;   w += (size_t)E * 4;
  float* s_arr = (float*)w; w += (size_t)n * 2 * 4;
  float* t_arr = (float*)w; w += (size_t)n * 2 * 4;
  ushort_t* AhP = (ushort_t*)w; w += (size_t)n * 128 * 2;
  ushort_t* AlP = (ushort_t*)w; w += (size_t)n * 128 * 2;
  __half2* h2h = (__half2*)w; w += (size_t)n * 64 * 4;
  __half* h16  = (__half*)w; w += (size_t)n * 64 * 2;
  ushort_t* h64h = (ushort_t*)w; w += (size_t)n * 64 * 2;
  ushort_t* h64l = (ushort_t*)w; w += (size_t)n * 64 * 2;
  ushort_t* wt0h = (ushort_t*)w; w += (size_t)128 * 512 * 2;
  ushort_t* wt0l = (ushort_t*)w; w += (size_t)128 * 512 * 2;
  ushort_t* wt1h = (ushort_t*)w; w += (size_t)128 * 128 * 2;
  ushort_t* wt1l = (ushort_t*)w; w += (size_t)128 * 128 * 2;
  ushort_t* wt2h = (ushort_t*)w; w += (size_t)64 * 128 * 2;
  ushort_t* wt2l = (ushort_t*)w; w += (size_t)64 * 128 * 2;
  ushort_t* wHh  = (ushort_t*)w; w += (size_t)128 * 64 * 2;
  ushort_t* wHl  = (ushort_t*)w; w += (size_t)128 * 64 * 2;

  float* s1 = s_arr;
  float* t1 = t_arr;

  float* out_h = (float*)d_out;
  float* out_v = out_h + (size_t)n * 64;
  float* out_t = out_v + (size_t)n * 64;

  // ---- setup: zero + (count + W preps) + scan + fill ----
  zero_kernel<<<NB, 256, 0, stream>>>(counts, n);
  setup_kernel<<<CNT_BLOCKS + 16 + 4 + 2 + 1 + 1, 256, 0, stream>>>(
      ei, counts, W0, wt0h, wt0l, W1, wt1h, wt1l, W2, wt2h, wt2l, Wv, Wt, wHh, wHl);
  scan_blocksum_kernel<<<NB, 256, 0, stream>>>(counts, bsums, n);
  scan_offsets_kernel<<<1, 256, 0, stream>>>(bsums, NB);
  scan_final_kernel<<<NBF, 256, 0, stream>>>(counts, bsums, row_ptr, cursor, n, E);
  fill_kernel<<<(E + 255) / 256, 256, 0, stream>>>(ei, row_ptr, cursor, col_src, E);

  const int wgrid = (n + 3) / 4;
  const int g64 = (n + 63) / 64;   // 782 blocks

  // ---- layer 0 ----
  gemm_att128_kernel<512, false><<<g64, 256, 0, stream>>>(x, nullptr, nullptr, wt0h, wt0l,
                                                          a_src0, a_dst0, h2h, s_arr, t_arr, n);
  agg2_kernel<<<wgrid, 256, 0, stream>>>(h2h, (const float2*)s_arr, (const float2*)t_arr,
                                         row_ptr, col_src, b0, AhP, AlP, n);

  // ---- layer 1 ----
  gemm_att128_kernel<128, true><<<g64, 256, 0, stream>>>(nullptr, AhP, AlP, wt1h, wt1l,
                                                         a_src1, a_dst1, h2h, s_arr, t_arr, n);
  agg2_kernel<<<wgrid, 256, 0, stream>>>(h2h, (const float2*)s_arr, (const float2*)t_arr,
                                         row_ptr, col_src, b1, AhP, AlP, n);

  // ---- layer 2 ----
  gemm_att64_kernel<<<g64, 256, 0, stream>>>(AhP, AlP, wt2h, wt2l, a_src2, a_dst2,
                                             h16, s1, t1, n);
  agg1_kernel<<<wgrid, 256, 0, stream>>>(h16, s1, t1, row_ptr, col_src, b2,
                                         out_h, h64h, h64l, n);

  // ---- both MLP heads ----
  gemm_heads_kernel<<<g64, 256, 0, stream>>>(h64h, h64l, wHh, wHl, bv, bt, out_v, out_t, n);
}